// Round 8
// baseline (1970.748 us; speedup 1.0000x reference)
//
#include <hip/hip_runtime.h>

#define B_ 256
#define S_ 64
#define I_ 256
#define H_ 1024
#define NODE_ 4
#define NB 256
#define NG 8     // row groups (32 batch rows each) -- data-decoupled, own barrier
#define GSZ 32   // blocks per group (one 32-col strip each)

typedef __attribute__((ext_vector_type(8))) short short8;
typedef __attribute__((ext_vector_type(4))) float f32x4;

// fp32 -> bf16 round-to-nearest-even on raw bits
__device__ __forceinline__ short f2bf(float f) {
    unsigned u = __float_as_uint(f);
    u += 0x7fffu + ((u >> 16) & 1u);
    return (short)(u >> 16);
}
__device__ __forceinline__ unsigned pack2(float a, float b) {
    return (unsigned)(unsigned short)f2bf(a) | ((unsigned)(unsigned short)f2bf(b) << 16);
}

// fast tanh: |err| ~1e-7 rel, negligible vs bf16 h quantization
__device__ __forceinline__ float ftanh(float x) {
    float e = __expf(2.0f * fabsf(x));
    float r = __builtin_fmaf(-2.0f, __builtin_amdgcn_rcpf(e + 1.0f), 1.0f);
    return copysignf(r, x);
}

__device__ __forceinline__ unsigned get_xcc() {
    unsigned x;
    asm volatile("s_getreg_b32 %0, hwreg(20, 0, 32)" : "=s"(x));  // HW_REG_XCC_ID
    return x & 0xfu;
}

// Verified round-6 barrier: agent-scope counter at LLC.
__device__ __forceinline__ void gbar_slow(unsigned* cnt, unsigned target) {
    __syncthreads();
    if (threadIdx.x == 0) {
        __hip_atomic_fetch_add(cnt, 1u, __ATOMIC_RELAXED, __HIP_MEMORY_SCOPE_AGENT);
        while (__hip_atomic_load(cnt, __ATOMIC_RELAXED, __HIP_MEMORY_SCOPE_AGENT) < target)
            __builtin_amdgcn_s_sleep(1);
    }
    __syncthreads();
}

// Dual-counter group barrier. fast: arrive on LOCAL (XCD-L2) counter AND agent
// counter; poll local via buffer_inv(L1)+plain load, fall back to agent poll
// every 16 iters -> termination guaranteed by the verified agent path even if
// local semantics misbehave. slow: agent-only (round-6 verified).
__device__ __forceinline__ void gbar2(unsigned* gcl, unsigned* gca, unsigned target, bool fast) {
    __syncthreads();   // drains vmcnt -> this block's h stores complete at L2/LLC
    if (threadIdx.x == 0) {
        if (fast) {
            unsigned one = 1;
            asm volatile("global_atomic_add %0, %1, off" :: "v"(gcl), "v"(one) : "memory");
            __hip_atomic_fetch_add(gca, 1u, __ATOMIC_RELAXED, __HIP_MEMORY_SCOPE_AGENT);
            unsigned v; unsigned it = 0;
            for (;;) {
                asm volatile("buffer_inv\n\t"
                             "s_waitcnt vmcnt(0)\n\t"
                             "global_load_dword %0, %1, off\n\t"
                             "s_waitcnt vmcnt(0)"
                             : "=&v"(v) : "v"(gcl) : "memory");
                if (v >= target) break;
                if ((++it & 15u) == 0 &&
                    __hip_atomic_load(gca, __ATOMIC_RELAXED, __HIP_MEMORY_SCOPE_AGENT) >= target)
                    break;
                __builtin_amdgcn_s_sleep(1);
            }
            // L1 fresh for all waves' subsequent plain stage loads
            asm volatile("buffer_inv\n\ts_waitcnt vmcnt(0)" ::: "memory");
        } else {
            __hip_atomic_fetch_add(gca, 1u, __ATOMIC_RELAXED, __HIP_MEMORY_SCOPE_AGENT);
            while (__hip_atomic_load(gca, __ATOMIC_RELAXED, __HIP_MEMORY_SCOPE_AGENT) < target)
                __builtin_amdgcn_s_sleep(1);
        }
    }
    __syncthreads();
}

__global__ __launch_bounds__(256, 1)
void odernn_persist(const float* __restrict__ x, const float* __restrict__ t,
                    const float* __restrict__ W_in, const float* __restrict__ b_in,
                    const float* __restrict__ W_h, const float* __restrict__ b_h,
                    const float* __restrict__ W_ode, const float* __restrict__ b_ode,
                    float* __restrict__ out,
                    unsigned short* __restrict__ h0buf, unsigned short* __restrict__ h1buf,
                    unsigned short* __restrict__ Whbf, unsigned short* __restrict__ Winbf,
                    unsigned* __restrict__ cnts)
{
    __shared__ short Wlds[32 * 1024];   // 64 KB: bf16 W_ode col-slice, XOR-swizzled
    __shared__ short Hlds[32 * 1024];   // 64 KB: staged h strip / publish gather

    const int tid = threadIdx.x;
    const int blk = blockIdx.x;
    const int bi = blk & 7;           // row group; blk%8 -> (checked) one XCD
    const int bj = blk >> 3;          // 0..31 col strip
    const int lane = tid & 63;
    const int wv = tid >> 6;
    const int wr = wv >> 1, wc = wv & 1;
    const int r16 = lane & 15, kg = lane >> 4;

    // ---- prologue A: convert W_h, W_in to bf16 in ws (disjoint chunks) ----
    {
        const int g = blk * 256 + tid;              // 0..65535
        const float* src = W_h + (size_t)g * 16;    // 16 floats each
        unsigned* dst = (unsigned*)Whbf + (size_t)g * 8;
#pragma unroll
        for (int i = 0; i < 4; ++i) {
            float4 v = *(const float4*)(src + i * 4);
            __hip_atomic_store(dst + i * 2,     pack2(v.x, v.y), __ATOMIC_RELAXED, __HIP_MEMORY_SCOPE_AGENT);
            __hip_atomic_store(dst + i * 2 + 1, pack2(v.z, v.w), __ATOMIC_RELAXED, __HIP_MEMORY_SCOPE_AGENT);
        }
        float4 v = *(const float4*)(W_in + (size_t)g * 4);
        unsigned* d2 = (unsigned*)Winbf + (size_t)g * 2;
        __hip_atomic_store(d2,     pack2(v.x, v.y), __ATOMIC_RELAXED, __HIP_MEMORY_SCOPE_AGENT);
        __hip_atomic_store(d2 + 1, pack2(v.z, v.w), __ATOMIC_RELAXED, __HIP_MEMORY_SCOPE_AGENT);
    }

    // ---- prologue B: stage W_ode[bj*32 .. +32][:] as bf16 into LDS ----
    {
        const int c = tid >> 3;
        const int ks = (tid & 7) * 128;
        const float* wsrc = W_ode + (size_t)(bj * 32 + c) * H_ + ks;
        for (int i = 0; i < 16; ++i) {
            float4 v0 = *(const float4*)(wsrc + i * 8);
            float4 v1 = *(const float4*)(wsrc + i * 8 + 4);
            short8 sv = { f2bf(v0.x), f2bf(v0.y), f2bf(v0.z), f2bf(v0.w),
                          f2bf(v1.x), f2bf(v1.y), f2bf(v1.z), f2bf(v1.w) };
            int idx = c * 1024 + ks + i * 8;
            *(short8*)&Wlds[idx ^ ((c & 7) << 3)] = sv;
        }
    }
    __syncthreads();

    // ---- replay hygiene + XCC publication (before global barrier) ----
    // buffer_inv sc1: drop stale L2 lines left by a previous graph replay
    // (h strips / local counters), BEFORE anything local is written this replay.
    if (tid == 0) {
        asm volatile("buffer_inv sc1\n\ts_waitcnt vmcnt(0)" ::: "memory");
        unsigned xc = get_xcc();
        __hip_atomic_fetch_max(&cnts[516 + bi], xc, __ATOMIC_RELAXED, __HIP_MEMORY_SCOPE_AGENT);
        __hip_atomic_fetch_max(&cnts[524],      xc, __ATOMIC_RELAXED, __HIP_MEMORY_SCOPE_AGENT);
        __hip_atomic_fetch_min(&cnts[525 + bi], xc, __ATOMIC_RELAXED, __HIP_MEMORY_SCOPE_AGENT);
        __hip_atomic_fetch_min(&cnts[533],      xc, __ATOMIC_RELAXED, __HIP_MEMORY_SCOPE_AGENT);
    }

    // global barrier #1: weights converted, all L2-invs done, xcc visible
    gbar_slow(&cnts[512], NB);

    // fast requires: group-uniform XCC AND globally non-uniform XCC
    const bool fast =
        (__hip_atomic_load(&cnts[524], __ATOMIC_RELAXED, __HIP_MEMORY_SCOPE_AGENT) !=
         __hip_atomic_load(&cnts[533], __ATOMIC_RELAXED, __HIP_MEMORY_SCOPE_AGENT)) &&
        (__hip_atomic_load(&cnts[516 + bi], __ATOMIC_RELAXED, __HIP_MEMORY_SCOPE_AGENT) ==
         __hip_atomic_load(&cnts[525 + bi], __ATOMIC_RELAXED, __HIP_MEMORY_SCOPE_AGENT));

    const int rowb = bi * 32 + wr * 16 + kg * 4;   // first of 4 output rows
    const int arow = bi * 32 + wr * 16 + r16;      // A-fragment row (batch)
    const int col  = bj * 32 + wc * 16 + r16;      // output column
    const int wb   = wc * 16 + r16;                // W-slice row for B-fragment

    const int hrow = wr * 16 + r16;                // A row within the 32-row strip
    const char* aBase = (const char*)Hlds + hrow * 2048;
    const int hswz = (hrow & 7) << 4;              // byte XOR for Hlds reads

    const float bodec = b_ode[col];
    const float binc  = b_in[col] + b_h[col];

    f32x4 hreg = {0.f, 0.f, 0.f, 0.f};
#pragma unroll
    for (int r = 0; r < 4; ++r)   // publish h0 = 0 (agent -> LLC; after all invs)
        __hip_atomic_store(&h0buf[(size_t)(rowb + r) * H_ + col], (unsigned short)0,
                           __ATOMIC_RELAXED, __HIP_MEMORY_SCOPE_AGENT);

    unsigned* gca = cnts + bi * 64;        // agent counter (LLC)
    unsigned* gcl = cnts + bi * 64 + 32;   // local counter (XCD L2, fast only)
    unsigned tar = GSZ;

    // group barrier #2: h0 zeros visible before first stage
    gbar2(gcl, gca, tar, fast); tar += GSZ;

    const unsigned short* hin = h0buf;
    unsigned short* hout = h1buf;

    // Stage this group's h strip (32 rows x 1024 bf16 = 64 KB) into Hlds.
    // fast: plain loads (L1 was invalidated at barrier exit -> hit XCD L2 where
    // producers' write-through stores landed). slow: verified agent loads (LLC).
    auto stage = [&](const unsigned short* hsrc) {
        if (fast) {
            const char* sp = (const char*)(hsrc + (size_t)bi * 32 * H_);
#pragma unroll
            for (int i = 0; i < 16; ++i) {
                f32x4 v = *(const f32x4*)(sp + i * 4096 + tid * 16);
                int off = i * 4096 + tid * 16;
                int row = off >> 11, c = off & 2047;
                *(f32x4*)((char*)Hlds + row * 2048 + (c ^ ((row & 7) << 4))) = v;
            }
        } else {
            const unsigned long long* src =
                (const unsigned long long*)(hsrc + (size_t)bi * 32 * H_);
            unsigned long long v[32];
#pragma unroll
            for (int i = 0; i < 32; ++i)
                v[i] = __hip_atomic_load(src + i * 256 + tid,
                                         __ATOMIC_RELAXED, __HIP_MEMORY_SCOPE_AGENT);
#pragma unroll
            for (int i = 0; i < 32; ++i) {
                int byte = i * 2048 + (((tid * 8) & 2047) ^ ((i & 7) << 4));
                *(unsigned long long*)((char*)Hlds + byte) = v[i];
            }
        }
        __syncthreads();
    };

    // Publish this block's 32x32 bf16 tile: gather in LDS, then 256 coalesced
    // u64 stores (32 cache lines vs 1024 scattered 2B transactions).
    auto publish = [&](unsigned short* dst, f32x4 pv) {
        __syncthreads();                    // Hlds MFMA reads done
        short* Hp = (short*)Hlds;
#pragma unroll
        for (int r = 0; r < 4; ++r)
            Hp[(wr * 16 + kg * 4 + r) * 32 + wc * 16 + r16] = f2bf(pv[r]);
        __syncthreads();
        const int row = tid >> 3, cg = tid & 7;
        unsigned long long v = *(unsigned long long*)&Hp[row * 32 + cg * 4];
        unsigned long long* d =
            (unsigned long long*)&dst[(size_t)(bi * 32 + row) * H_ + bj * 32 + cg * 4];
        if (fast) *d = v;   // write-through -> XCD L2
        else __hip_atomic_store(d, v, __ATOMIC_RELAXED, __HIP_MEMORY_SCOPE_AGENT);
    };

    for (int s = 0; s < S_; ++s) {
        if (s > 0) {
            const float dth = (t[s] - t[s - 1]) * 0.25f;
            for (int e = 0; e < NODE_; ++e) {
                stage(hin);
                f32x4 acc = {0.f, 0.f, 0.f, 0.f};
#pragma unroll
                for (int k0 = 0; k0 < H_; k0 += 32) {
                    short8 a = *(const short8*)(aBase + (((k0 + kg * 8) * 2) ^ hswz));
                    short8 b = *(const short8*)&Wlds[(wb * 1024 + k0 + kg * 8) ^ ((wb & 7) << 3)];
                    acc = __builtin_amdgcn_mfma_f32_16x16x32_bf16(a, b, acc, 0, 0, 0);
                }
#pragma unroll
                for (int r = 0; r < 4; ++r)
                    hreg[r] += dth * ftanh(acc[r] + bodec);
                publish(hout, hreg);
                gbar2(gcl, gca, tar, fast); tar += GSZ;
                const unsigned short* tmp = hin; hin = hout; hout = (unsigned short*)tmp;
            }
        }
        // ---- update: h = tanh(x_s @ W_in^T + h @ W_h^T + b_in + b_h) ----
        {
            stage(hin);
            f32x4 acc = {0.f, 0.f, 0.f, 0.f};
            const unsigned short* whB = Whbf + (size_t)col * H_ + kg * 8;
#pragma unroll 8
            for (int k0 = 0; k0 < H_; k0 += 32) {
                short8 a = *(const short8*)(aBase + (((k0 + kg * 8) * 2) ^ hswz));
                short8 b = *(const short8*)(whB + k0);
                acc = __builtin_amdgcn_mfma_f32_16x16x32_bf16(a, b, acc, 0, 0, 0);
            }
            const float* xB = x + ((size_t)arow * S_ + s) * I_ + kg * 8;
            const unsigned short* wiB = Winbf + (size_t)col * I_ + kg * 8;
#pragma unroll
            for (int k2 = 0; k2 < I_; k2 += 32) {
                float4 a0 = *(const float4*)(xB + k2);
                float4 a1 = *(const float4*)(xB + k2 + 4);
                short8 a = { f2bf(a0.x), f2bf(a0.y), f2bf(a0.z), f2bf(a0.w),
                             f2bf(a1.x), f2bf(a1.y), f2bf(a1.z), f2bf(a1.w) };
                short8 b = *(const short8*)(wiB + k2);
                acc = __builtin_amdgcn_mfma_f32_16x16x32_bf16(a, b, acc, 0, 0, 0);
            }
            const bool last = (s == S_ - 1);
            f32x4 hv;
#pragma unroll
            for (int r = 0; r < 4; ++r) {
                hv[r] = ftanh(acc[r] + binc);
                hreg[r] = hv[r];
            }
            if (last) {
#pragma unroll
                for (int r = 0; r < 4; ++r)
                    out[(size_t)(rowb + r) * H_ + col] = hv[r];
            } else {
                publish(hout, hv);
                gbar2(gcl, gca, tar, fast); tar += GSZ;
                const unsigned short* tmp = hin; hin = hout; hout = (unsigned short*)tmp;
            }
        }
    }

    // restore local counter to 0 so the next graph replay starts clean even if
    // buffer_inv sc1 turns out to write back (not discard) dirty lines.
    if (fast && tid == 0 && bj == 0) {
        unsigned fin = tar - GSZ;   // final gcl value
        asm volatile("global_atomic_sub %0, %1, off" :: "v"(gcl), "v"(fin) : "memory");
    }
}

extern "C" void kernel_launch(void* const* d_in, const int* in_sizes, int n_in,
                              void* d_out, int out_size, void* d_ws, size_t ws_size,
                              hipStream_t stream) {
    const float* x     = (const float*)d_in[0];
    const float* t     = (const float*)d_in[1];
    const float* W_in  = (const float*)d_in[2];
    const float* b_in  = (const float*)d_in[3];
    const float* W_h   = (const float*)d_in[4];
    const float* b_h   = (const float*)d_in[5];
    const float* W_ode = (const float*)d_in[6];
    const float* b_ode = (const float*)d_in[7];

    unsigned short* h0    = (unsigned short*)d_ws;
    unsigned short* h1    = h0 + (size_t)B_ * H_;
    unsigned short* Whbf  = h1 + (size_t)B_ * H_;
    unsigned short* Winbf = Whbf + (size_t)H_ * H_;
    unsigned* cnts = (unsigned*)(Winbf + (size_t)H_ * I_);
    // layout (uints): [bi*64]=gca, [bi*64+32]=gcl (bi=0..7), [512]=global,
    // [516..523]=xmax[8], [524]=xmaxg, [525..532]=xmin[8], [533]=xming

    (void)hipMemsetAsync(cnts, 0, 525 * sizeof(unsigned), stream);
    (void)hipMemsetAsync(cnts + 525, 0xFF, 9 * sizeof(unsigned), stream);

    odernn_persist<<<dim3(NB), dim3(256), 0, stream>>>(
        x, t, W_in, b_in, W_h, b_h, W_ode, b_ode,
        (float*)d_out, h0, h1, Whbf, Winbf, cnts);
}

// Round 9
// 1439.605 us; speedup vs baseline: 1.3690x; 1.3690x over previous
//
#include <hip/hip_runtime.h>

#define B_ 256
#define S_ 64
#define I_ 256
#define H_ 1024
#define NODE_ 4
#define NB 256
#define NG 8     // row groups (32 batch rows each) -- data-decoupled, own barrier
#define GSZ 32   // blocks per group (one 32-col strip each)

typedef __attribute__((ext_vector_type(8))) short short8;
typedef __attribute__((ext_vector_type(4))) float f32x4;

// fp32 -> bf16 round-to-nearest-even on raw bits
__device__ __forceinline__ short f2bf(float f) {
    unsigned u = __float_as_uint(f);
    u += 0x7fffu + ((u >> 16) & 1u);
    return (short)(u >> 16);
}
__device__ __forceinline__ unsigned pack2(float a, float b) {
    return (unsigned)(unsigned short)f2bf(a) | ((unsigned)(unsigned short)f2bf(b) << 16);
}

// fast tanh: |err| ~1e-7 rel, negligible vs bf16 h quantization
__device__ __forceinline__ float ftanh(float x) {
    float e = __expf(2.0f * fabsf(x));
    float r = __builtin_fmaf(-2.0f, __builtin_amdgcn_rcpf(e + 1.0f), 1.0f);
    return copysignf(r, x);
}

__device__ __forceinline__ unsigned get_xcc() {
    unsigned x;
    asm volatile("s_getreg_b32 %0, hwreg(20, 0, 32)" : "=s"(x));  // HW_REG_XCC_ID
    return x & 0xfu;
}

// Verified round-6 barrier: agent-scope counter at LLC.
__device__ __forceinline__ void gbar_slow(unsigned* cnt, unsigned target) {
    __syncthreads();
    if (threadIdx.x == 0) {
        __hip_atomic_fetch_add(cnt, 1u, __ATOMIC_RELAXED, __HIP_MEMORY_SCOPE_AGENT);
        while (__hip_atomic_load(cnt, __ATOMIC_RELAXED, __HIP_MEMORY_SCOPE_AGENT) < target)
            __builtin_amdgcn_s_sleep(1);
    }
    __syncthreads();
}

// Dual-counter group barrier. fast: arrive on BOTH counters (always -- so either
// counter alone is a complete barrier); poll the LOCAL (XCD-L2) counter with an
// sc0 load (bypasses L1, reads the L2 where unflagged atomics execute). Sticky
// fallback to agent polling after 256 failed polls -> cannot hang.
__device__ __forceinline__ void gbar2(unsigned* gcl, unsigned* gca, unsigned target,
                                      bool fast, bool& use_local) {
    __syncthreads();   // drains vmcnt -> this block's h stores complete at L2/LLC
    if (threadIdx.x == 0) {
        if (fast) {
            unsigned one = 1;
            asm volatile("global_atomic_add %0, %1, off" :: "v"(gcl), "v"(one) : "memory");
            __hip_atomic_fetch_add(gca, 1u, __ATOMIC_RELAXED, __HIP_MEMORY_SCOPE_AGENT);
            if (use_local) {
                unsigned v, it = 0;
                for (;;) {
                    asm volatile("global_load_dword %0, %1, off sc0\n\ts_waitcnt vmcnt(0)"
                                 : "=&v"(v) : "v"(gcl) : "memory");
                    if (v >= target) break;
                    if (++it >= 256u) {
                        if (__hip_atomic_load(gca, __ATOMIC_RELAXED,
                                              __HIP_MEMORY_SCOPE_AGENT) >= target) {
                            use_local = false;   // sticky: local detection unreliable
                            break;
                        }
                        it = 0;
                    }
                    __builtin_amdgcn_s_sleep(1);
                }
            } else {
                while (__hip_atomic_load(gca, __ATOMIC_RELAXED, __HIP_MEMORY_SCOPE_AGENT) < target)
                    __builtin_amdgcn_s_sleep(1);
            }
        } else {
            __hip_atomic_fetch_add(gca, 1u, __ATOMIC_RELAXED, __HIP_MEMORY_SCOPE_AGENT);
            while (__hip_atomic_load(gca, __ATOMIC_RELAXED, __HIP_MEMORY_SCOPE_AGENT) < target)
                __builtin_amdgcn_s_sleep(1);
        }
    }
    __syncthreads();
}

__global__ __launch_bounds__(256, 1)
void odernn_persist(const float* __restrict__ x, const float* __restrict__ t,
                    const float* __restrict__ W_in, const float* __restrict__ b_in,
                    const float* __restrict__ W_h, const float* __restrict__ b_h,
                    const float* __restrict__ W_ode, const float* __restrict__ b_ode,
                    float* __restrict__ out,
                    unsigned short* __restrict__ h0buf, unsigned short* __restrict__ h1buf,
                    unsigned short* __restrict__ Whbf, unsigned short* __restrict__ Winbf,
                    unsigned* __restrict__ cnts)
{
    __shared__ short Wlds[32 * 1024];   // 64 KB: bf16 W_ode col-slice, XOR-swizzled
    __shared__ short Hlds[32 * 1024];   // 64 KB: staged h strip / publish gather

    const int tid = threadIdx.x;
    const int blk = blockIdx.x;
    const int bi = blk & 7;           // row group; blk%8 -> (checked) one XCD
    const int bj = blk >> 3;          // 0..31 col strip
    const int lane = tid & 63;
    const int wv = tid >> 6;
    const int wr = wv >> 1, wc = wv & 1;
    const int r16 = lane & 15, kg = lane >> 4;

    // ---- prologue A: convert W_h, W_in to bf16 in ws (disjoint chunks) ----
    {
        const int g = blk * 256 + tid;              // 0..65535
        const float* src = W_h + (size_t)g * 16;    // 16 floats each
        unsigned* dst = (unsigned*)Whbf + (size_t)g * 8;
#pragma unroll
        for (int i = 0; i < 4; ++i) {
            float4 v = *(const float4*)(src + i * 4);
            __hip_atomic_store(dst + i * 2,     pack2(v.x, v.y), __ATOMIC_RELAXED, __HIP_MEMORY_SCOPE_AGENT);
            __hip_atomic_store(dst + i * 2 + 1, pack2(v.z, v.w), __ATOMIC_RELAXED, __HIP_MEMORY_SCOPE_AGENT);
        }
        float4 v = *(const float4*)(W_in + (size_t)g * 4);
        unsigned* d2 = (unsigned*)Winbf + (size_t)g * 2;
        __hip_atomic_store(d2,     pack2(v.x, v.y), __ATOMIC_RELAXED, __HIP_MEMORY_SCOPE_AGENT);
        __hip_atomic_store(d2 + 1, pack2(v.z, v.w), __ATOMIC_RELAXED, __HIP_MEMORY_SCOPE_AGENT);
    }

    // ---- prologue B: stage W_ode[bj*32 .. +32][:] as bf16 into LDS ----
    {
        const int c = tid >> 3;
        const int ks = (tid & 7) * 128;
        const float* wsrc = W_ode + (size_t)(bj * 32 + c) * H_ + ks;
        for (int i = 0; i < 16; ++i) {
            float4 v0 = *(const float4*)(wsrc + i * 8);
            float4 v1 = *(const float4*)(wsrc + i * 8 + 4);
            short8 sv = { f2bf(v0.x), f2bf(v0.y), f2bf(v0.z), f2bf(v0.w),
                          f2bf(v1.x), f2bf(v1.y), f2bf(v1.z), f2bf(v1.w) };
            int idx = c * 1024 + ks + i * 8;
            *(short8*)&Wlds[idx ^ ((c & 7) << 3)] = sv;
        }
    }
    __syncthreads();

    // ---- replay hygiene + XCC publication (before global barrier) ----
    // buffer_inv sc1: discard stale L2 lines from a previous graph replay
    // BEFORE any plain (L2-dirty) writes of this replay happen anywhere.
    if (tid == 0) {
        asm volatile("buffer_inv sc1\n\ts_waitcnt vmcnt(0)" ::: "memory");
        unsigned xc = get_xcc();
        __hip_atomic_fetch_max(&cnts[516 + bi], xc, __ATOMIC_RELAXED, __HIP_MEMORY_SCOPE_AGENT);
        __hip_atomic_fetch_max(&cnts[524],      xc, __ATOMIC_RELAXED, __HIP_MEMORY_SCOPE_AGENT);
        __hip_atomic_fetch_min(&cnts[525 + bi], xc, __ATOMIC_RELAXED, __HIP_MEMORY_SCOPE_AGENT);
        __hip_atomic_fetch_min(&cnts[533],      xc, __ATOMIC_RELAXED, __HIP_MEMORY_SCOPE_AGENT);
    }

    // global barrier #1: weights converted, all L2-invs done, xcc visible
    gbar_slow(&cnts[512], NB);

    // fast requires: group-uniform XCC AND globally non-uniform XCC
    const bool fast =
        (__hip_atomic_load(&cnts[524], __ATOMIC_RELAXED, __HIP_MEMORY_SCOPE_AGENT) !=
         __hip_atomic_load(&cnts[533], __ATOMIC_RELAXED, __HIP_MEMORY_SCOPE_AGENT)) &&
        (__hip_atomic_load(&cnts[516 + bi], __ATOMIC_RELAXED, __HIP_MEMORY_SCOPE_AGENT) ==
         __hip_atomic_load(&cnts[525 + bi], __ATOMIC_RELAXED, __HIP_MEMORY_SCOPE_AGENT));
    bool use_local = true;

    const int rowb = bi * 32 + wr * 16 + kg * 4;   // first of 4 output rows
    const int arow = bi * 32 + wr * 16 + r16;      // A-fragment row (batch)
    const int col  = bj * 32 + wc * 16 + r16;      // output column
    const int wb   = wc * 16 + r16;                // W-slice row for B-fragment

    const int hrow = wr * 16 + r16;                // A row within the 32-row strip
    const char* aBase = (const char*)Hlds + hrow * 2048;
    const int hswz = (hrow & 7) << 4;              // byte XOR for Hlds reads

    const float bodec = b_ode[col];
    const float binc  = b_in[col] + b_h[col];

    f32x4 hreg = {0.f, 0.f, 0.f, 0.f};
    // publish h0 = 0 AFTER barrier #1 (all invs done). fast: plain stores land
    // dirty in this XCD's L2 (consumers read via sc0). slow: agent -> LLC.
#pragma unroll
    for (int r = 0; r < 4; ++r) {
        if (fast) h0buf[(size_t)(rowb + r) * H_ + col] = 0;
        else __hip_atomic_store(&h0buf[(size_t)(rowb + r) * H_ + col], (unsigned short)0,
                                __ATOMIC_RELAXED, __HIP_MEMORY_SCOPE_AGENT);
    }

    unsigned* gca = cnts + bi * 64;        // agent counter (LLC)
    unsigned* gcl = cnts + bi * 64 + 32;   // local counter (XCD L2, fast only)
    unsigned tar = GSZ;

    // group barrier #2: h0 zeros visible before first stage
    gbar2(gcl, gca, tar, fast, use_local); tar += GSZ;

    const unsigned short* hin = h0buf;
    unsigned short* hout = h1buf;

    // Stage this group's h strip (32 rows x 1024 bf16 = 64 KB) into Hlds.
    // fast: sc0 loads (bypass L1, read this XCD's L2 where producers' plain
    // write-through stores landed). slow: verified agent loads (LLC).
    auto stage = [&](const unsigned short* hsrc) {
        if (fast) {
            const char* sp = (const char*)(hsrc + (size_t)bi * 32 * H_) + tid * 16;
            f32x4 v[16];
#pragma unroll
            for (int i = 0; i < 16; ++i)
                asm volatile("global_load_dwordx4 %0, %1, off sc0"
                             : "=&v"(v[i]) : "v"(sp + i * 4096));
            asm volatile("s_waitcnt vmcnt(0)" ::: "memory");
            __builtin_amdgcn_sched_barrier(0);
#pragma unroll
            for (int i = 0; i < 16; ++i) {
                int off = i * 4096 + tid * 16;
                int row = off >> 11, c = off & 2047;
                *(f32x4*)((char*)Hlds + row * 2048 + (c ^ ((row & 7) << 4))) = v[i];
            }
        } else {
            const unsigned long long* src =
                (const unsigned long long*)(hsrc + (size_t)bi * 32 * H_);
            unsigned long long v[32];
#pragma unroll
            for (int i = 0; i < 32; ++i)
                v[i] = __hip_atomic_load(src + i * 256 + tid,
                                         __ATOMIC_RELAXED, __HIP_MEMORY_SCOPE_AGENT);
#pragma unroll
            for (int i = 0; i < 32; ++i) {
                int byte = i * 2048 + (((tid * 8) & 2047) ^ ((i & 7) << 4));
                *(unsigned long long*)((char*)Hlds + byte) = v[i];
            }
        }
        __syncthreads();
    };

    // Publish this block's 32x32 bf16 tile: gather in LDS, then 256 coalesced
    // u64 stores. fast: plain write-through -> XCD L2. slow: agent -> LLC.
    auto publish = [&](unsigned short* dst, f32x4 pv) {
        __syncthreads();                    // Hlds MFMA reads done
        short* Hp = (short*)Hlds;
#pragma unroll
        for (int r = 0; r < 4; ++r)
            Hp[(wr * 16 + kg * 4 + r) * 32 + wc * 16 + r16] = f2bf(pv[r]);
        __syncthreads();
        const int row = tid >> 3, cg = tid & 7;
        unsigned long long v = *(unsigned long long*)&Hp[row * 32 + cg * 4];
        unsigned long long* d =
            (unsigned long long*)&dst[(size_t)(bi * 32 + row) * H_ + bj * 32 + cg * 4];
        if (fast) *d = v;
        else __hip_atomic_store(d, v, __ATOMIC_RELAXED, __HIP_MEMORY_SCOPE_AGENT);
    };

    for (int s = 0; s < S_; ++s) {
        if (s > 0) {
            const float dth = (t[s] - t[s - 1]) * 0.25f;
            for (int e = 0; e < NODE_; ++e) {
                stage(hin);
                f32x4 acc = {0.f, 0.f, 0.f, 0.f};
#pragma unroll
                for (int k0 = 0; k0 < H_; k0 += 32) {
                    short8 a = *(const short8*)(aBase + (((k0 + kg * 8) * 2) ^ hswz));
                    short8 b = *(const short8*)&Wlds[(wb * 1024 + k0 + kg * 8) ^ ((wb & 7) << 3)];
                    acc = __builtin_amdgcn_mfma_f32_16x16x32_bf16(a, b, acc, 0, 0, 0);
                }
#pragma unroll
                for (int r = 0; r < 4; ++r)
                    hreg[r] += dth * ftanh(acc[r] + bodec);
                publish(hout, hreg);
                gbar2(gcl, gca, tar, fast, use_local); tar += GSZ;
                const unsigned short* tmp = hin; hin = hout; hout = (unsigned short*)tmp;
            }
        }
        // ---- update: h = tanh(x_s @ W_in^T + h @ W_h^T + b_in + b_h) ----
        {
            stage(hin);
            f32x4 acc = {0.f, 0.f, 0.f, 0.f};
            const unsigned short* whB = Whbf + (size_t)col * H_ + kg * 8;
#pragma unroll 8
            for (int k0 = 0; k0 < H_; k0 += 32) {
                short8 a = *(const short8*)(aBase + (((k0 + kg * 8) * 2) ^ hswz));
                short8 b = *(const short8*)(whB + k0);
                acc = __builtin_amdgcn_mfma_f32_16x16x32_bf16(a, b, acc, 0, 0, 0);
            }
            const float* xB = x + ((size_t)arow * S_ + s) * I_ + kg * 8;
            const unsigned short* wiB = Winbf + (size_t)col * I_ + kg * 8;
#pragma unroll
            for (int k2 = 0; k2 < I_; k2 += 32) {
                float4 a0 = *(const float4*)(xB + k2);
                float4 a1 = *(const float4*)(xB + k2 + 4);
                short8 a = { f2bf(a0.x), f2bf(a0.y), f2bf(a0.z), f2bf(a0.w),
                             f2bf(a1.x), f2bf(a1.y), f2bf(a1.z), f2bf(a1.w) };
                short8 b = *(const short8*)(wiB + k2);
                acc = __builtin_amdgcn_mfma_f32_16x16x32_bf16(a, b, acc, 0, 0, 0);
            }
            const bool last = (s == S_ - 1);
            f32x4 hv;
#pragma unroll
            for (int r = 0; r < 4; ++r) {
                hv[r] = ftanh(acc[r] + binc);
                hreg[r] = hv[r];
            }
            if (last) {
#pragma unroll
                for (int r = 0; r < 4; ++r)
                    out[(size_t)(rowb + r) * H_ + col] = hv[r];
            } else {
                publish(hout, hv);
                gbar2(gcl, gca, tar, fast, use_local); tar += GSZ;
                const unsigned short* tmp = hin; hin = hout; hout = (unsigned short*)tmp;
            }
        }
    }

    // restore local counter to 0 for the next graph replay (memset can't reach
    // dirty XCD-L2 lines; the subtract leaves the dirty line at exactly 0).
    if (fast && tid == 0 && bj == 0) {
        unsigned fin = tar - GSZ;   // final gcl value
        asm volatile("global_atomic_sub %0, %1, off" :: "v"(gcl), "v"(fin) : "memory");
    }
}

extern "C" void kernel_launch(void* const* d_in, const int* in_sizes, int n_in,
                              void* d_out, int out_size, void* d_ws, size_t ws_size,
                              hipStream_t stream) {
    const float* x     = (const float*)d_in[0];
    const float* t     = (const float*)d_in[1];
    const float* W_in  = (const float*)d_in[2];
    const float* b_in  = (const float*)d_in[3];
    const float* W_h   = (const float*)d_in[4];
    const float* b_h   = (const float*)d_in[5];
    const float* W_ode = (const float*)d_in[6];
    const float* b_ode = (const float*)d_in[7];

    unsigned short* h0    = (unsigned short*)d_ws;
    unsigned short* h1    = h0 + (size_t)B_ * H_;
    unsigned short* Whbf  = h1 + (size_t)B_ * H_;
    unsigned short* Winbf = Whbf + (size_t)H_ * H_;
    unsigned* cnts = (unsigned*)(Winbf + (size_t)H_ * I_);
    // layout (uints): [bi*64]=gca, [bi*64+32]=gcl (bi=0..7), [512]=global,
    // [516..523]=xmax[8], [524]=xmaxg, [525..532]=xmin[8], [533]=xming

    (void)hipMemsetAsync(cnts, 0, 525 * sizeof(unsigned), stream);
    (void)hipMemsetAsync(cnts + 525, 0xFF, 9 * sizeof(unsigned), stream);

    odernn_persist<<<dim3(NB), dim3(256), 0, stream>>>(
        x, t, W_in, b_in, W_h, b_h, W_ode, b_ode,
        (float*)d_out, h0, h1, Whbf, Winbf, cnts);
}